// Round 6
// baseline (1318.486 us; speedup 1.0000x reference)
//
#include <hip/hip_runtime.h>
#include <hip/hip_bf16.h>
#include <math.h>

typedef __bf16 bf16_t;
typedef float floatx4 __attribute__((ext_vector_type(4)));
typedef bf16_t bf16x8 __attribute__((ext_vector_type(8)));

typedef __attribute__((address_space(1))) void g_void;
typedef __attribute__((address_space(3))) void lds_void;

__device__ __forceinline__ void ldg_lds16(const bf16_t* g, bf16_t* l) {
    __builtin_amdgcn_global_load_lds((g_void*)g, (lds_void*)l, 16, 0, 0);
}

__device__ __forceinline__ void unpack4(uint2 r, float* o) {
    o[0] = __uint_as_float((r.x & 0xffffu) << 16); o[1] = __uint_as_float(r.x & 0xffff0000u);
    o[2] = __uint_as_float((r.y & 0xffffu) << 16); o[3] = __uint_as_float(r.y & 0xffff0000u);
}

// ---------------- weight fp32 -> bf16 conversion --------------------------------------
__global__ void cvt_weights(const float* __restrict__ sqkvw, const float* __restrict__ sow,
                            const float* __restrict__ sl1w,  const float* __restrict__ sl2w,
                            const float* __restrict__ tqkvw, const float* __restrict__ tow,
                            const float* __restrict__ tl1w,  const float* __restrict__ tl2w,
                            bf16_t* __restrict__ dst) {
    int i = blockIdx.x * 256 + threadIdx.x;  // total 1310720
    float v;
    if      (i <  393216) v = sqkvw[i];
    else if (i <  524288) v = sow  [i -  393216];
    else if (i <  589824) v = sl1w [i -  524288];
    else if (i <  655360) v = sl2w [i -  589824];
    else if (i < 1048576) v = tqkvw[i -  655360];
    else if (i < 1179648) v = tow  [i - 1048576];
    else if (i < 1245184) v = tl1w [i - 1179648];
    else                  v = tl2w [i - 1245184];
    dst[i] = (bf16_t)v;
}

// ---------------- embed: gelu(moveinfo @ w_in^T + b_in), cls=1e-5, layout [BC,9,256] ----
__global__ void embed_k(const float* __restrict__ mv, const float* __restrict__ w_in,
                        const float* __restrict__ b_in, bf16_t* __restrict__ x, int b0) {
    int blk = blockIdx.x; int d = threadIdx.x;
    int tok = blk % 9; int lb = blk / 9;
    size_t oidx = (size_t)blk * 256 + d;
    if (tok == 0) { x[oidx] = (bf16_t)1e-5f; return; }
    int bb = b0 + lb; int t = bb >> 8; int s = bb & 255;   // b = t*256+s
    int n = s * 8 + (tok - 1);
    float m0 = mv[((size_t)n * 64 + t) * 2];
    float m1 = mv[((size_t)n * 64 + t) * 2 + 1];
    float v = m0 * w_in[2 * d] + m1 * w_in[2 * d + 1] + b_in[d];
    v = 0.5f * v * (1.0f + erff(v * 0.70710678118654752f));  // exact gelu
    x[oidx] = (bf16_t)v;
}

// ---------------- cls extract: t_x[s*64+t, :] = x[lb, 0, :] (bf16 + fp32) ---------------
__global__ void cls_k(const bf16_t* __restrict__ x, bf16_t* __restrict__ txb,
                      float* __restrict__ txf, int b0) {
    int lb = blockIdx.x; int d = threadIdx.x;
    int bb = b0 + lb; int t = bb >> 8; int s = bb & 255;
    bf16_t v = x[(size_t)lb * 2304 + d];
    size_t di = ((size_t)(s * 64 + t)) * 256 + d;
    txb[di] = v;
    txf[di] = (float)v;
}

// ---------------- plain GEMM: C = A @ W^T + bias (opt relu), bf16 out ------------------
// 1-D grid, XCD-grouped: all NT n-blocks of an m-tile land on the same XCD (g%8 const)
// so the A-tile is fetched into that XCD's L2 once. MFMA operands swapped so each lane
// holds 4 consecutive output cols -> packed dwordx2 stores.
__global__ __launch_bounds__(256) void gemm_bt(const bf16_t* __restrict__ A,
                                               const bf16_t* __restrict__ W,
                                               const float* __restrict__ bias,
                                               bf16_t* __restrict__ C,
                                               int M, int N, int K, int relu) {
    __shared__ __align__(16) bf16_t As[4096];  // [128][32]
    __shared__ __align__(16) bf16_t Ws[4096];  // [128][32]
    int MT = M >> 7, NT = N >> 7;
    int g = blockIdx.x;
    int m_t, n_t;
    if ((MT & 7) == 0) {
        int x = g & 7, q = g >> 3;
        m_t = (q / NT) * 8 + x;
        n_t = q % NT;
    } else {
        m_t = g / NT; n_t = g % NT;
    }
    int tid = threadIdx.x;
    int lane = tid & 63;
    int wave = tid >> 6;
    int m0 = m_t * 128;
    int n0 = n_t * 128;
    int wm = (wave & 1) * 64;
    int wn = (wave >> 1) * 64;
    int arow = tid >> 2;
    int acol = (tid & 3) * 8;
    int fm = lane & 15;
    int fq = lane >> 4;

    floatx4 acc[4][4] = {};

    const bf16_t* Ag = A + (size_t)(m0 + arow) * K + acol;
    const bf16_t* Wg = W + (size_t)(n0 + arow) * K + acol;

    for (int k0 = 0; k0 < K; k0 += 32) {
        __syncthreads();
        ldg_lds16(Ag + k0,                  &As[tid * 8]);
        ldg_lds16(Ag + k0 + (size_t)64 * K, &As[2048 + tid * 8]);
        ldg_lds16(Wg + k0,                  &Ws[tid * 8]);
        ldg_lds16(Wg + k0 + (size_t)64 * K, &Ws[2048 + tid * 8]);
        __syncthreads();

        bf16x8 af[4], wf[4];
#pragma unroll
        for (int mi = 0; mi < 4; mi++)
            af[mi] = *(const bf16x8*)&As[(wm + mi * 16 + fm) * 32 + fq * 8];
#pragma unroll
        for (int ni = 0; ni < 4; ni++)
            wf[ni] = *(const bf16x8*)&Ws[(wn + ni * 16 + fm) * 32 + fq * 8];
#pragma unroll
        for (int mi = 0; mi < 4; mi++)
#pragma unroll
            for (int ni = 0; ni < 4; ni++)
                acc[mi][ni] = __builtin_amdgcn_mfma_f32_16x16x32_bf16(wf[ni], af[mi], acc[mi][ni], 0, 0, 0);
    }

    // swapped layout: lane holds C[row = wm+mi*16+fm][cols = wn+ni*16+fq*4 .. +3]
#pragma unroll
    for (int mi = 0; mi < 4; mi++) {
        int row = m0 + wm + mi * 16 + fm;
#pragma unroll
        for (int ni = 0; ni < 4; ni++) {
            int colb = n0 + wn + ni * 16 + fq * 4;
            float4 b4 = *(const float4*)(bias + colb);
            float v0 = acc[mi][ni][0] + b4.x;
            float v1 = acc[mi][ni][1] + b4.y;
            float v2 = acc[mi][ni][2] + b4.z;
            float v3 = acc[mi][ni][3] + b4.w;
            if (relu) {
                v0 = fmaxf(v0, 0.f); v1 = fmaxf(v1, 0.f);
                v2 = fmaxf(v2, 0.f); v3 = fmaxf(v3, 0.f);
            }
            bf16_t t4[4] = {(bf16_t)v0, (bf16_t)v1, (bf16_t)v2, (bf16_t)v3};
            *(uint2*)(C + (size_t)row * N + colb) = *(uint2*)t4;
        }
    }
}

// ---------------- attention, seqlen 9: 4 seqs / 256-thread block, bf16 LDS -------------
__global__ __launch_bounds__(256) void attn9_k(const bf16_t* __restrict__ qkv,
                                               bf16_t* __restrict__ ao) {
    __shared__ __align__(16) bf16_t sb[27648];  // 4 * 9 * 768
    int b = blockIdx.x; int tid = threadIdx.x;
    const uint4* src = (const uint4*)(qkv + (size_t)b * 27648);
    uint4* dstl = (uint4*)sb;
    for (int c = tid; c < 3456; c += 256) dstl[c] = src[c];
    __syncthreads();
    for (int p = tid; p < 288; p += 256) {
        int s = p / 72; int rem = p - s * 72; int h = rem / 9; int i = rem - h * 9;
        const bf16_t* B = sb + s * 6912;
        const bf16_t* qp = B + i * 768 + h * 32;
        float qf[32];
#pragma unroll
        for (int c = 0; c < 4; c++) {
            bf16x8 t8 = *(const bf16x8*)(qp + c * 8);
#pragma unroll
            for (int e = 0; e < 8; e++) qf[c * 8 + e] = (float)t8[e];
        }
        float sc[9]; float mx = -1e30f;
#pragma unroll
        for (int j = 0; j < 9; j++) {
            const bf16_t* kp = B + j * 768 + 256 + h * 32;
            float d = 0.f;
#pragma unroll
            for (int c = 0; c < 4; c++) {
                bf16x8 t8 = *(const bf16x8*)(kp + c * 8);
#pragma unroll
                for (int e = 0; e < 8; e++) d += qf[c * 8 + e] * (float)t8[e];
            }
            d *= 0.17677669529663687f;
            sc[j] = d; mx = fmaxf(mx, d);
        }
        float den = 0.f;
#pragma unroll
        for (int j = 0; j < 9; j++) { sc[j] = __expf(sc[j] - mx); den += sc[j]; }
        float inv = 1.0f / den;
        float of[32] = {};
#pragma unroll
        for (int j = 0; j < 9; j++) {
            const bf16_t* vp = B + j * 768 + 512 + h * 32;
            float w = sc[j];
#pragma unroll
            for (int c = 0; c < 4; c++) {
                bf16x8 t8 = *(const bf16x8*)(vp + c * 8);
#pragma unroll
                for (int e = 0; e < 8; e++) of[c * 8 + e] += w * (float)t8[e];
            }
        }
        bf16_t* dst = ao + ((size_t)(b * 4 + s) * 9 + i) * 256 + h * 32;
#pragma unroll
        for (int c = 0; c < 4; c++) {
            bf16x8 o8;
#pragma unroll
            for (int e = 0; e < 8; e++) o8[e] = (bf16_t)(of[c * 8 + e] * inv);
            *(bf16x8*)(dst + c * 8) = o8;
        }
    }
}

// ---------------- attention, seqlen 64 (stage C) ---------------------------------------
__global__ __launch_bounds__(64) void attn64_k(const bf16_t* __restrict__ qkv,
                                               bf16_t* __restrict__ ao) {
    __shared__ float kk[64][32];
    __shared__ float vv[64][32];
    int s = blockIdx.x >> 3, h = blockIdx.x & 7;
    int i = threadIdx.x;
    const bf16_t* base = qkv + ((size_t)(s * 64 + i)) * 768 + h * 32;
    float qf[32];
#pragma unroll
    for (int c = 0; c < 4; c++) {
        bf16x8 t8 = *(const bf16x8*)(base + c * 8);
#pragma unroll
        for (int e = 0; e < 8; e++) qf[c * 8 + e] = (float)t8[e];
    }
#pragma unroll
    for (int c = 0; c < 4; c++) {
        bf16x8 t8 = *(const bf16x8*)(base + 256 + c * 8);
#pragma unroll
        for (int e = 0; e < 8; e++) kk[i][c * 8 + e] = (float)t8[e];
    }
#pragma unroll
    for (int c = 0; c < 4; c++) {
        bf16x8 t8 = *(const bf16x8*)(base + 512 + c * 8);
#pragma unroll
        for (int e = 0; e < 8; e++) vv[i][c * 8 + e] = (float)t8[e];
    }
    __syncthreads();
    float sc[64]; float mx = -1e30f;
#pragma unroll
    for (int j = 0; j < 64; j++) {
        float d = 0.f;
#pragma unroll
        for (int dd = 0; dd < 32; dd++) d += qf[dd] * kk[j][dd];
        d *= 0.17677669529663687f;
        sc[j] = d; mx = fmaxf(mx, d);
    }
    float den = 0.f;
#pragma unroll
    for (int j = 0; j < 64; j++) { sc[j] = __expf(sc[j] - mx); den += sc[j]; }
    float inv = 1.0f / den;
    bf16_t* dst = ao + ((size_t)(s * 64 + i)) * 256 + h * 32;
#pragma unroll
    for (int dd = 0; dd < 32; dd++) {
        float o = 0.f;
#pragma unroll
        for (int j = 0; j < 64; j++) o += sc[j] * vv[j][dd];
        dst[dd] = (bf16_t)(o * inv);
    }
}

// ---------------- residual + LayerNorm: out = LN(xin+add)*w+b; one wave per row --------
__global__ __launch_bounds__(256) void resln_k(const bf16_t* __restrict__ xin_bf,
                                               const float* __restrict__ xin_f,
                                               const bf16_t* __restrict__ add,
                                               const float* __restrict__ w,
                                               const float* __restrict__ b,
                                               bf16_t* __restrict__ out_bf,
                                               float* __restrict__ out_f) {
    int row = blockIdx.x * 4 + (threadIdx.x >> 6);
    int lane = threadIdx.x & 63;
    size_t base = (size_t)row * 256 + lane * 4;
    float xv[4], av[4], v[4];
    if (xin_f) {
        float4 t = *(const float4*)(xin_f + base);
        xv[0] = t.x; xv[1] = t.y; xv[2] = t.z; xv[3] = t.w;
    } else {
        unpack4(*(const uint2*)(xin_bf + base), xv);
    }
    unpack4(*(const uint2*)(add + base), av);
    float s = 0.f, ss = 0.f;
#pragma unroll
    for (int i = 0; i < 4; i++) { v[i] = xv[i] + av[i]; s += v[i]; ss += v[i] * v[i]; }
#pragma unroll
    for (int off = 32; off > 0; off >>= 1) {
        s += __shfl_xor(s, off, 64);
        ss += __shfl_xor(ss, off, 64);
    }
    float mean = s * (1.f / 256.f);
    float var = ss * (1.f / 256.f) - mean * mean;
    float inv = rsqrtf(var + 1e-5f);
    float o[4];
#pragma unroll
    for (int i = 0; i < 4; i++)
        o[i] = (v[i] - mean) * inv * w[lane * 4 + i] + b[lane * 4 + i];
    if (out_bf) {
        bf16_t tmp[4] = {(bf16_t)o[0], (bf16_t)o[1], (bf16_t)o[2], (bf16_t)o[3]};
        *(uint2*)(out_bf + base) = *(uint2*)tmp;
    }
    if (out_f) {
        float4 t; t.x = o[0]; t.y = o[1]; t.z = o[2]; t.w = o[3];
        *(float4*)(out_f + base) = t;
    }
}

// ------------------------------------------------------------------------------------------
extern "C" void kernel_launch(void* const* d_in, const int* in_sizes, int n_in,
                              void* d_out, int out_size, void* d_ws, size_t ws_size,
                              hipStream_t stream) {
    const float* mv   = (const float*)d_in[0];
    const float* w_in = (const float*)d_in[2];
    const float* b_in = (const float*)d_in[3];
    const float* sp[12]; const float* tp[12];
    for (int i = 0; i < 12; i++) { sp[i] = (const float*)d_in[4 + i]; tp[i] = (const float*)d_in[16 + i]; }
    // idx: 0 qkvw, 1 qkvb, 2 ow, 3 ob, 4 l1w, 5 l1b, 6 l2w, 7 l2b, 8 ln1w, 9 ln1b, 10 ln2w, 11 ln2b

    bf16_t* wbf = (bf16_t*)d_ws;              // 1310720 bf16 weights
    bf16_t* txb = wbf + 1310720;              // t_x bf16: 16384*256
    float*  txf = (float*)(txb + 4194304);    // t_x fp32: 16384*256
    bf16_t* pool = (bf16_t*)(txf + 4194304);

    long long headB = 2621440LL + 8388608LL + 16777216LL;  // wbf + txb + txf bytes
    long long cand[5] = {16384, 8192, 4096, 2048, 1024};
    int BC = 1024;
    for (int c = 0; c < 5; c++) {
        long long poolB = cand[c] * 11520LL * 2;            // x(2304)+qkv(6912)+ao(2304) bf16
        if (poolB < 33554432LL) poolB = 33554432LL;         // stage-C floor
        if ((size_t)(headB + poolB) <= ws_size) { BC = (int)cand[c]; break; }
    }

    cvt_weights<<<5120, 256, 0, stream>>>(sp[0], sp[2], sp[4], sp[6], tp[0], tp[2], tp[4], tp[6], wbf);

    const int M = BC * 9;
    const int MTb = M / 128;
    bf16_t* xc    = pool;
    bf16_t* qkvb_ = pool + (long long)BC * 2304;
    bf16_t* aob   = qkvb_ + (long long)BC * 6912;
    bf16_t* pob   = qkvb_;                          // proj out (qkv region free after attn9)
    bf16_t* hb    = qkvb_;                          // ffn hidden (pob dead after resln)
    bf16_t* f2b   = qkvb_ + (long long)M * 128;     // ffn2 out (after hb)

    for (int b0 = 0; b0 < 16384; b0 += BC) {
        embed_k<<<dim3(M), 256, 0, stream>>>(mv, w_in, b_in, xc, b0);
        for (int l = 0; l < 2; l++) {
            const bf16_t* wq = wbf + 0      + l * 196608;
            const bf16_t* wo = wbf + 393216 + l * 65536;
            const bf16_t* w1 = wbf + 524288 + l * 32768;
            const bf16_t* w2 = wbf + 589824 + l * 32768;
            gemm_bt<<<dim3(MTb * 6), 256, 0, stream>>>(xc, wq, sp[1] + l * 768, qkvb_, M, 768, 256, 0);
            attn9_k<<<dim3(BC / 4), 256, 0, stream>>>(qkvb_, aob);
            gemm_bt<<<dim3(MTb * 2), 256, 0, stream>>>(aob, wo, sp[3] + l * 256, pob, M, 256, 256, 0);
            resln_k<<<dim3(M / 4), 256, 0, stream>>>(xc, (const float*)nullptr, pob,
                                                     sp[8] + l * 256, sp[9] + l * 256,
                                                     xc, (float*)nullptr);
            gemm_bt<<<dim3(MTb * 1), 256, 0, stream>>>(xc, w1, sp[5] + l * 128, hb, M, 128, 256, 1);
            gemm_bt<<<dim3(MTb * 2), 256, 0, stream>>>(hb, w2, sp[7] + l * 256, f2b, M, 256, 128, 0);
            resln_k<<<dim3(M / 4), 256, 0, stream>>>(xc, (const float*)nullptr, f2b,
                                                     sp[10] + l * 256, sp[11] + l * 256,
                                                     xc, (float*)nullptr);
        }
        cls_k<<<dim3(BC), 256, 0, stream>>>(xc, txb, txf, b0);
    }

    // ---- stage C: 256 seqs x 64 tokens, fp32 residual sidecar ----
    const int Mt = 16384;
    bf16_t* tqkv = pool;                    // 16384*768
    bf16_t* tao  = pool + 12582912;         // 16384*256
    bf16_t* tpo  = pool;                    // proj out (tqkv region free after attn64)
    bf16_t* tth  = pool + 4194304;          // ffn hidden 16384*128
    bf16_t* tf2  = pool + 4194304 + 2097152;// ffn2 out 16384*256
    for (int l = 0; l < 2; l++) {
        gemm_bt<<<dim3(128 * 6), 256, 0, stream>>>(txb, wbf + 655360 + l * 196608, tp[1] + l * 768,
                                                   tqkv, Mt, 768, 256, 0);
        attn64_k<<<dim3(2048), 64, 0, stream>>>(tqkv, tao);
        gemm_bt<<<dim3(128 * 2), 256, 0, stream>>>(tao, wbf + 1048576 + l * 65536, tp[3] + l * 256,
                                                   tpo, Mt, 256, 256, 0);
        resln_k<<<dim3(4096), 256, 0, stream>>>((const bf16_t*)nullptr, txf, tpo,
                                                tp[8] + l * 256, tp[9] + l * 256,
                                                txb, txf);
        gemm_bt<<<dim3(128 * 1), 256, 0, stream>>>(txb, wbf + 1179648 + l * 32768, tp[5] + l * 128,
                                                   tth, Mt, 128, 256, 1);
        gemm_bt<<<dim3(128 * 2), 256, 0, stream>>>(tth, wbf + 1245184 + l * 32768, tp[7] + l * 256,
                                                   tf2, Mt, 256, 128, 0);
        if (l == 0)
            resln_k<<<dim3(4096), 256, 0, stream>>>((const bf16_t*)nullptr, txf, tf2,
                                                    tp[10] + l * 256, tp[11] + l * 256,
                                                    txb, txf);
        else
            resln_k<<<dim3(4096), 256, 0, stream>>>((const bf16_t*)nullptr, txf, tf2,
                                                    tp[10] + l * 256, tp[11] + l * 256,
                                                    (bf16_t*)nullptr, (float*)d_out);
    }
}

// Round 7
// 1270.363 us; speedup vs baseline: 1.0379x; 1.0379x over previous
//
#include <hip/hip_runtime.h>
#include <hip/hip_bf16.h>
#include <math.h>

typedef __bf16 bf16_t;
typedef float floatx4 __attribute__((ext_vector_type(4)));
typedef bf16_t bf16x8 __attribute__((ext_vector_type(8)));

typedef __attribute__((address_space(1))) void g_void;
typedef __attribute__((address_space(3))) void lds_void;

__device__ __forceinline__ void ldg_lds16(const bf16_t* g, bf16_t* l) {
    __builtin_amdgcn_global_load_lds((g_void*)g, (lds_void*)l, 16, 0, 0);
}

__device__ __forceinline__ void unpack4(uint2 r, float* o) {
    o[0] = __uint_as_float((r.x & 0xffffu) << 16); o[1] = __uint_as_float(r.x & 0xffff0000u);
    o[2] = __uint_as_float((r.y & 0xffffu) << 16); o[3] = __uint_as_float(r.y & 0xffff0000u);
}

// ---------------- weight fp32 -> bf16 conversion --------------------------------------
__global__ void cvt_weights(const float* __restrict__ sqkvw, const float* __restrict__ sow,
                            const float* __restrict__ sl1w,  const float* __restrict__ sl2w,
                            const float* __restrict__ tqkvw, const float* __restrict__ tow,
                            const float* __restrict__ tl1w,  const float* __restrict__ tl2w,
                            bf16_t* __restrict__ dst) {
    int i = blockIdx.x * 256 + threadIdx.x;  // total 1310720
    float v;
    if      (i <  393216) v = sqkvw[i];
    else if (i <  524288) v = sow  [i -  393216];
    else if (i <  589824) v = sl1w [i -  524288];
    else if (i <  655360) v = sl2w [i -  589824];
    else if (i < 1048576) v = tqkvw[i -  655360];
    else if (i < 1179648) v = tow  [i - 1048576];
    else if (i < 1245184) v = tl1w [i - 1179648];
    else                  v = tl2w [i - 1245184];
    dst[i] = (bf16_t)v;
}

// ---------------- embed: gelu(moveinfo @ w_in^T + b_in), cls=1e-5, layout [BC,9,256] ----
__global__ void embed_k(const float* __restrict__ mv, const float* __restrict__ w_in,
                        const float* __restrict__ b_in, bf16_t* __restrict__ x, int b0) {
    int blk = blockIdx.x; int d = threadIdx.x;
    int tok = blk % 9; int lb = blk / 9;
    size_t oidx = (size_t)blk * 256 + d;
    if (tok == 0) { x[oidx] = (bf16_t)1e-5f; return; }
    int bb = b0 + lb; int t = bb >> 8; int s = bb & 255;   // b = t*256+s
    int n = s * 8 + (tok - 1);
    float m0 = mv[((size_t)n * 64 + t) * 2];
    float m1 = mv[((size_t)n * 64 + t) * 2 + 1];
    float v = m0 * w_in[2 * d] + m1 * w_in[2 * d + 1] + b_in[d];
    v = 0.5f * v * (1.0f + erff(v * 0.70710678118654752f));  // exact gelu
    x[oidx] = (bf16_t)v;
}

// ---------------- cls extract: t_x[s*64+t, :] = x[lb, 0, :] (bf16 + fp32) ---------------
__global__ void cls_k(const bf16_t* __restrict__ x, bf16_t* __restrict__ txb,
                      float* __restrict__ txf, int b0) {
    int lb = blockIdx.x; int d = threadIdx.x;
    int bb = b0 + lb; int t = bb >> 8; int s = bb & 255;
    bf16_t v = x[(size_t)lb * 2304 + d];
    size_t di = ((size_t)(s * 64 + t)) * 256 + d;
    txb[di] = v;
    txf[di] = (float)v;
}

// ---------------- plain GEMM: C = A @ W^T + bias (opt relu), bf16 out ------------------
// 2-D grid, n fast (R5 layout). Swapped MFMA operands: lane holds 4 consecutive cols.
__global__ __launch_bounds__(256) void gemm_bt(const bf16_t* __restrict__ A,
                                               const bf16_t* __restrict__ W,
                                               const float* __restrict__ bias,
                                               bf16_t* __restrict__ C,
                                               int M, int N, int K, int relu) {
    __shared__ __align__(16) bf16_t As[4096];  // [128][32]
    __shared__ __align__(16) bf16_t Ws[4096];  // [128][32]
    int tid = threadIdx.x;
    int lane = tid & 63;
    int wave = tid >> 6;
    int m0 = blockIdx.y * 128;
    int n0 = blockIdx.x * 128;
    int wm = (wave & 1) * 64;
    int wn = (wave >> 1) * 64;
    int arow = tid >> 2;
    int acol = (tid & 3) * 8;
    int fm = lane & 15;
    int fq = lane >> 4;

    floatx4 acc[4][4] = {};

    const bf16_t* Ag = A + (size_t)(m0 + arow) * K + acol;
    const bf16_t* Wg = W + (size_t)(n0 + arow) * K + acol;

    for (int k0 = 0; k0 < K; k0 += 32) {
        __syncthreads();
        ldg_lds16(Ag + k0,                  &As[tid * 8]);
        ldg_lds16(Ag + k0 + (size_t)64 * K, &As[2048 + tid * 8]);
        ldg_lds16(Wg + k0,                  &Ws[tid * 8]);
        ldg_lds16(Wg + k0 + (size_t)64 * K, &Ws[2048 + tid * 8]);
        __syncthreads();

        bf16x8 af[4], wf[4];
#pragma unroll
        for (int mi = 0; mi < 4; mi++)
            af[mi] = *(const bf16x8*)&As[(wm + mi * 16 + fm) * 32 + fq * 8];
#pragma unroll
        for (int ni = 0; ni < 4; ni++)
            wf[ni] = *(const bf16x8*)&Ws[(wn + ni * 16 + fm) * 32 + fq * 8];
#pragma unroll
        for (int mi = 0; mi < 4; mi++)
#pragma unroll
            for (int ni = 0; ni < 4; ni++)
                acc[mi][ni] = __builtin_amdgcn_mfma_f32_16x16x32_bf16(wf[ni], af[mi], acc[mi][ni], 0, 0, 0);
    }

    // swapped layout: lane holds C[row = wm+mi*16+fm][cols = wn+ni*16+fq*4 .. +3]
#pragma unroll
    for (int mi = 0; mi < 4; mi++) {
        int row = m0 + wm + mi * 16 + fm;
#pragma unroll
        for (int ni = 0; ni < 4; ni++) {
            int colb = n0 + wn + ni * 16 + fq * 4;
            float4 b4 = *(const float4*)(bias + colb);
            float v0 = acc[mi][ni][0] + b4.x;
            float v1 = acc[mi][ni][1] + b4.y;
            float v2 = acc[mi][ni][2] + b4.z;
            float v3 = acc[mi][ni][3] + b4.w;
            if (relu) {
                v0 = fmaxf(v0, 0.f); v1 = fmaxf(v1, 0.f);
                v2 = fmaxf(v2, 0.f); v3 = fmaxf(v3, 0.f);
            }
            bf16_t t4[4] = {(bf16_t)v0, (bf16_t)v1, (bf16_t)v2, (bf16_t)v3};
            *(uint2*)(C + (size_t)row * N + colb) = *(uint2*)t4;
        }
    }
}

// ---------------- attention, seqlen 9: 4 seqs / 256-thread block, bf16 LDS -------------
__global__ __launch_bounds__(256) void attn9_k(const bf16_t* __restrict__ qkv,
                                               bf16_t* __restrict__ ao) {
    __shared__ __align__(16) bf16_t sb[27648];  // 4 * 9 * 768
    int b = blockIdx.x; int tid = threadIdx.x;
    const uint4* src = (const uint4*)(qkv + (size_t)b * 27648);
    uint4* dstl = (uint4*)sb;
    for (int c = tid; c < 3456; c += 256) dstl[c] = src[c];
    __syncthreads();
    for (int p = tid; p < 288; p += 256) {
        int s = p / 72; int rem = p - s * 72; int h = rem / 9; int i = rem - h * 9;
        const bf16_t* B = sb + s * 6912;
        const bf16_t* qp = B + i * 768 + h * 32;
        float qf[32];
#pragma unroll
        for (int c = 0; c < 4; c++) {
            bf16x8 t8 = *(const bf16x8*)(qp + c * 8);
#pragma unroll
            for (int e = 0; e < 8; e++) qf[c * 8 + e] = (float)t8[e];
        }
        float sc[9]; float mx = -1e30f;
#pragma unroll
        for (int j = 0; j < 9; j++) {
            const bf16_t* kp = B + j * 768 + 256 + h * 32;
            float d = 0.f;
#pragma unroll
            for (int c = 0; c < 4; c++) {
                bf16x8 t8 = *(const bf16x8*)(kp + c * 8);
#pragma unroll
                for (int e = 0; e < 8; e++) d += qf[c * 8 + e] * (float)t8[e];
            }
            d *= 0.17677669529663687f;
            sc[j] = d; mx = fmaxf(mx, d);
        }
        float den = 0.f;
#pragma unroll
        for (int j = 0; j < 9; j++) { sc[j] = __expf(sc[j] - mx); den += sc[j]; }
        float inv = 1.0f / den;
        float of[32] = {};
#pragma unroll
        for (int j = 0; j < 9; j++) {
            const bf16_t* vp = B + j * 768 + 512 + h * 32;
            float w = sc[j];
#pragma unroll
            for (int c = 0; c < 4; c++) {
                bf16x8 t8 = *(const bf16x8*)(vp + c * 8);
#pragma unroll
                for (int e = 0; e < 8; e++) of[c * 8 + e] += w * (float)t8[e];
            }
        }
        bf16_t* dst = ao + ((size_t)(b * 4 + s) * 9 + i) * 256 + h * 32;
#pragma unroll
        for (int c = 0; c < 4; c++) {
            bf16x8 o8;
#pragma unroll
            for (int e = 0; e < 8; e++) o8[e] = (bf16_t)(of[c * 8 + e] * inv);
            *(bf16x8*)(dst + c * 8) = o8;
        }
    }
}

// ---------------- attention, seqlen 64 (stage C) ---------------------------------------
// Block = 256 threads = 4 waves per (seq, head). Waves split the j (key) dimension for
// scores (16 each), merge softmax stats via LDS, then split the output dim for PV.
__global__ __launch_bounds__(256) void attn64_k(const bf16_t* __restrict__ qkv,
                                                bf16_t* __restrict__ ao) {
    __shared__ __align__(16) float kk[64 * 36];   // padded rows: 16B-aligned, 8-way store conflicts max
    __shared__ __align__(16) float vv[64 * 36];
    __shared__ __align__(16) float pp[64 * 64];   // P[j][i]
    __shared__ float mloc[4 * 64];
    __shared__ float sloc[4 * 64];
    int s = blockIdx.x >> 3, h = blockIdx.x & 7;
    int t = threadIdx.x;
    int i = t & 63;          // lane = query row / output row
    int wq = t >> 6;         // wave index = j-quarter (phase 1) / dim-chunk (phase 2)

    // ---- stage K,V (fp32) into LDS; thread t loads 16B of K and V ----
    {
        int r = t >> 2, c = t & 3;
        const bf16_t* kb = qkv + ((size_t)(s * 64 + r)) * 768 + h * 32 + 256 + c * 8;
        bf16x8 k8 = *(const bf16x8*)kb;
        bf16x8 v8 = *(const bf16x8*)(kb + 256);
        float* kd = &kk[r * 36 + c * 8];
        float* vd = &vv[r * 36 + c * 8];
#pragma unroll
        for (int e = 0; e < 8; e++) { kd[e] = (float)k8[e]; vd[e] = (float)v8[e]; }
    }
    // ---- load Q for row i ----
    const bf16_t* qb = qkv + ((size_t)(s * 64 + i)) * 768 + h * 32;
    float qf[32];
#pragma unroll
    for (int c = 0; c < 4; c++) {
        bf16x8 t8 = *(const bf16x8*)(qb + c * 8);
#pragma unroll
        for (int e = 0; e < 8; e++) qf[c * 8 + e] = (float)t8[e];
    }
    __syncthreads();

    // ---- scores for this wave's 16 keys ----
    float sc[16]; float mx = -1e30f;
#pragma unroll
    for (int jj = 0; jj < 16; jj++) {
        int j = wq * 16 + jj;
        const float* kr = &kk[j * 36];
        float d = 0.f;
#pragma unroll
        for (int c = 0; c < 8; c++) {
            float4 k4 = *(const float4*)(kr + c * 4);   // broadcast read
            d += qf[c*4+0]*k4.x + qf[c*4+1]*k4.y + qf[c*4+2]*k4.z + qf[c*4+3]*k4.w;
        }
        d *= 0.17677669529663687f;
        sc[jj] = d; mx = fmaxf(mx, d);
    }
    float se = 0.f;
#pragma unroll
    for (int jj = 0; jj < 16; jj++) se += __expf(sc[jj] - mx);
    mloc[wq * 64 + i] = mx;
    sloc[wq * 64 + i] = se;
    __syncthreads();

    // ---- global max & denominator for row i ----
    float m0 = mloc[i], m1 = mloc[64 + i], m2 = mloc[128 + i], m3 = mloc[192 + i];
    float gm = fmaxf(fmaxf(m0, m1), fmaxf(m2, m3));
    float D = sloc[i] * __expf(m0 - gm) + sloc[64 + i] * __expf(m1 - gm)
            + sloc[128 + i] * __expf(m2 - gm) + sloc[192 + i] * __expf(m3 - gm);

    // ---- write P[j][i] ----
#pragma unroll
    for (int jj = 0; jj < 16; jj++)
        pp[(wq * 16 + jj) * 64 + i] = __expf(sc[jj] - gm);
    __syncthreads();

    // ---- PV: thread (row i, dim chunk wq*8..) over all 64 keys ----
    float of[8] = {};
    for (int j = 0; j < 64; j++) {
        float w = pp[j * 64 + i];                  // stride-1 across lanes: conflict-free
        const float* vr = &vv[j * 36 + wq * 8];    // broadcast
        float4 va = *(const float4*)vr;
        float4 vb = *(const float4*)(vr + 4);
        of[0] += w * va.x; of[1] += w * va.y; of[2] += w * va.z; of[3] += w * va.w;
        of[4] += w * vb.x; of[5] += w * vb.y; of[6] += w * vb.z; of[7] += w * vb.w;
    }
    float invD = 1.0f / D;
    bf16_t o8[8];
#pragma unroll
    for (int e = 0; e < 8; e++) o8[e] = (bf16_t)(of[e] * invD);
    *(uint4*)(ao + ((size_t)(s * 64 + i)) * 256 + h * 32 + wq * 8) = *(uint4*)o8;
}

// ---------------- residual + LayerNorm: out = LN(xin+add)*w+b; one wave per row --------
__global__ __launch_bounds__(256) void resln_k(const bf16_t* __restrict__ xin_bf,
                                               const float* __restrict__ xin_f,
                                               const bf16_t* __restrict__ add,
                                               const float* __restrict__ w,
                                               const float* __restrict__ b,
                                               bf16_t* __restrict__ out_bf,
                                               float* __restrict__ out_f) {
    int row = blockIdx.x * 4 + (threadIdx.x >> 6);
    int lane = threadIdx.x & 63;
    size_t base = (size_t)row * 256 + lane * 4;
    float xv[4], av[4], v[4];
    if (xin_f) {
        float4 t = *(const float4*)(xin_f + base);
        xv[0] = t.x; xv[1] = t.y; xv[2] = t.z; xv[3] = t.w;
    } else {
        unpack4(*(const uint2*)(xin_bf + base), xv);
    }
    unpack4(*(const uint2*)(add + base), av);
    float s = 0.f, ss = 0.f;
#pragma unroll
    for (int i = 0; i < 4; i++) { v[i] = xv[i] + av[i]; s += v[i]; ss += v[i] * v[i]; }
#pragma unroll
    for (int off = 32; off > 0; off >>= 1) {
        s += __shfl_xor(s, off, 64);
        ss += __shfl_xor(ss, off, 64);
    }
    float mean = s * (1.f / 256.f);
    float var = ss * (1.f / 256.f) - mean * mean;
    float inv = rsqrtf(var + 1e-5f);
    float o[4];
#pragma unroll
    for (int i = 0; i < 4; i++)
        o[i] = (v[i] - mean) * inv * w[lane * 4 + i] + b[lane * 4 + i];
    if (out_bf) {
        bf16_t tmp[4] = {(bf16_t)o[0], (bf16_t)o[1], (bf16_t)o[2], (bf16_t)o[3]};
        *(uint2*)(out_bf + base) = *(uint2*)tmp;
    }
    if (out_f) {
        float4 t; t.x = o[0]; t.y = o[1]; t.z = o[2]; t.w = o[3];
        *(float4*)(out_f + base) = t;
    }
}

// ------------------------------------------------------------------------------------------
extern "C" void kernel_launch(void* const* d_in, const int* in_sizes, int n_in,
                              void* d_out, int out_size, void* d_ws, size_t ws_size,
                              hipStream_t stream) {
    const float* mv   = (const float*)d_in[0];
    const float* w_in = (const float*)d_in[2];
    const float* b_in = (const float*)d_in[3];
    const float* sp[12]; const float* tp[12];
    for (int i = 0; i < 12; i++) { sp[i] = (const float*)d_in[4 + i]; tp[i] = (const float*)d_in[16 + i]; }
    // idx: 0 qkvw, 1 qkvb, 2 ow, 3 ob, 4 l1w, 5 l1b, 6 l2w, 7 l2b, 8 ln1w, 9 ln1b, 10 ln2w, 11 ln2b

    bf16_t* wbf = (bf16_t*)d_ws;              // 1310720 bf16 weights
    bf16_t* txb = wbf + 1310720;              // t_x bf16: 16384*256
    float*  txf = (float*)(txb + 4194304);    // t_x fp32: 16384*256
    bf16_t* pool = (bf16_t*)(txf + 4194304);

    long long headB = 2621440LL + 8388608LL + 16777216LL;  // wbf + txb + txf bytes
    long long cand[5] = {16384, 8192, 4096, 2048, 1024};
    int BC = 1024;
    for (int c = 0; c < 5; c++) {
        long long poolB = cand[c] * 11520LL * 2;            // x(2304)+qkv(6912)+ao(2304) bf16
        if (poolB < 33554432LL) poolB = 33554432LL;         // stage-C floor
        if ((size_t)(headB + poolB) <= ws_size) { BC = (int)cand[c]; break; }
    }

    cvt_weights<<<5120, 256, 0, stream>>>(sp[0], sp[2], sp[4], sp[6], tp[0], tp[2], tp[4], tp[6], wbf);

    const int M = BC * 9;
    const int MTb = M / 128;
    bf16_t* xc    = pool;
    bf16_t* qkvb_ = pool + (long long)BC * 2304;
    bf16_t* aob   = qkvb_ + (long long)BC * 6912;
    bf16_t* pob   = qkvb_;                          // proj out (qkv region free after attn9)
    bf16_t* hb    = qkvb_;                          // ffn hidden (pob dead after resln)
    bf16_t* f2b   = qkvb_ + (long long)M * 128;     // ffn2 out (after hb)

    for (int b0 = 0; b0 < 16384; b0 += BC) {
        embed_k<<<dim3(M), 256, 0, stream>>>(mv, w_in, b_in, xc, b0);
        for (int l = 0; l < 2; l++) {
            const bf16_t* wq = wbf + 0      + l * 196608;
            const bf16_t* wo = wbf + 393216 + l * 65536;
            const bf16_t* w1 = wbf + 524288 + l * 32768;
            const bf16_t* w2 = wbf + 589824 + l * 32768;
            gemm_bt<<<dim3(6, MTb), 256, 0, stream>>>(xc, wq, sp[1] + l * 768, qkvb_, M, 768, 256, 0);
            attn9_k<<<dim3(BC / 4), 256, 0, stream>>>(qkvb_, aob);
            gemm_bt<<<dim3(2, MTb), 256, 0, stream>>>(aob, wo, sp[3] + l * 256, pob, M, 256, 256, 0);
            resln_k<<<dim3(M / 4), 256, 0, stream>>>(xc, (const float*)nullptr, pob,
                                                     sp[8] + l * 256, sp[9] + l * 256,
                                                     xc, (float*)nullptr);
            gemm_bt<<<dim3(1, MTb), 256, 0, stream>>>(xc, w1, sp[5] + l * 128, hb, M, 128, 256, 1);
            gemm_bt<<<dim3(2, MTb), 256, 0, stream>>>(hb, w2, sp[7] + l * 256, f2b, M, 256, 128, 0);
            resln_k<<<dim3(M / 4), 256, 0, stream>>>(xc, (const float*)nullptr, f2b,
                                                     sp[10] + l * 256, sp[11] + l * 256,
                                                     xc, (float*)nullptr);
        }
        cls_k<<<dim3(BC), 256, 0, stream>>>(xc, txb, txf, b0);
    }

    // ---- stage C: 256 seqs x 64 tokens, fp32 residual sidecar ----
    const int Mt = 16384;
    bf16_t* tqkv = pool;                    // 16384*768
    bf16_t* tao  = pool + 12582912;         // 16384*256
    bf16_t* tpo  = pool;                    // proj out (tqkv region free after attn64)
    bf16_t* tth  = pool + 4194304;          // ffn hidden 16384*128
    bf16_t* tf2  = pool + 4194304 + 2097152;// ffn2 out 16384*256
    for (int l = 0; l < 2; l++) {
        gemm_bt<<<dim3(6, 128), 256, 0, stream>>>(txb, wbf + 655360 + l * 196608, tp[1] + l * 768,
                                                  tqkv, Mt, 768, 256, 0);
        attn64_k<<<dim3(2048), 256, 0, stream>>>(tqkv, tao);
        gemm_bt<<<dim3(2, 128), 256, 0, stream>>>(tao, wbf + 1048576 + l * 65536, tp[3] + l * 256,
                                                  tpo, Mt, 256, 256, 0);
        resln_k<<<dim3(4096), 256, 0, stream>>>((const bf16_t*)nullptr, txf, tpo,
                                                tp[8] + l * 256, tp[9] + l * 256,
                                                txb, txf);
        gemm_bt<<<dim3(1, 128), 256, 0, stream>>>(txb, wbf + 1179648 + l * 32768, tp[5] + l * 128,
                                                  tth, Mt, 128, 256, 1);
        gemm_bt<<<dim3(2, 128), 256, 0, stream>>>(tth, wbf + 1245184 + l * 32768, tp[7] + l * 256,
                                                  tf2, Mt, 256, 128, 0);
        if (l == 0)
            resln_k<<<dim3(4096), 256, 0, stream>>>((const bf16_t*)nullptr, txf, tf2,
                                                    tp[10] + l * 256, tp[11] + l * 256,
                                                    txb, txf);
        else
            resln_k<<<dim3(4096), 256, 0, stream>>>((const bf16_t*)nullptr, txf, tf2,
                                                    tp[10] + l * 256, tp[11] + l * 256,
                                                    (bf16_t*)nullptr, (float*)d_out);
    }
}

// Round 8
// 1213.680 us; speedup vs baseline: 1.0864x; 1.0467x over previous
//
#include <hip/hip_runtime.h>
#include <hip/hip_bf16.h>
#include <math.h>

typedef __bf16 bf16_t;
typedef float floatx4 __attribute__((ext_vector_type(4)));
typedef bf16_t bf16x8 __attribute__((ext_vector_type(8)));

typedef __attribute__((address_space(1))) void g_void;
typedef __attribute__((address_space(3))) void lds_void;

__device__ __forceinline__ void ldg_lds16(const bf16_t* g, bf16_t* l) {
    __builtin_amdgcn_global_load_lds((g_void*)g, (lds_void*)l, 16, 0, 0);
}

__device__ __forceinline__ void unpack4(uint2 r, float* o) {
    o[0] = __uint_as_float((r.x & 0xffffu) << 16); o[1] = __uint_as_float(r.x & 0xffff0000u);
    o[2] = __uint_as_float((r.y & 0xffffu) << 16); o[3] = __uint_as_float(r.y & 0xffff0000u);
}

// ---------------- weight fp32 -> bf16 conversion --------------------------------------
__global__ void cvt_weights(const float* __restrict__ sqkvw, const float* __restrict__ sow,
                            const float* __restrict__ sl1w,  const float* __restrict__ sl2w,
                            const float* __restrict__ tqkvw, const float* __restrict__ tow,
                            const float* __restrict__ tl1w,  const float* __restrict__ tl2w,
                            bf16_t* __restrict__ dst) {
    int i = blockIdx.x * 256 + threadIdx.x;  // total 1310720
    float v;
    if      (i <  393216) v = sqkvw[i];
    else if (i <  524288) v = sow  [i -  393216];
    else if (i <  589824) v = sl1w [i -  524288];
    else if (i <  655360) v = sl2w [i -  589824];
    else if (i < 1048576) v = tqkvw[i -  655360];
    else if (i < 1179648) v = tow  [i - 1048576];
    else if (i < 1245184) v = tl1w [i - 1179648];
    else                  v = tl2w [i - 1245184];
    dst[i] = (bf16_t)v;
}

// ---------------- embed: gelu(moveinfo @ w_in^T + b_in), cls=1e-5, layout [BC,9,256] ----
__global__ void embed_k(const float* __restrict__ mv, const float* __restrict__ w_in,
                        const float* __restrict__ b_in, bf16_t* __restrict__ x, int b0) {
    int blk = blockIdx.x; int d = threadIdx.x;
    int tok = blk % 9; int lb = blk / 9;
    size_t oidx = (size_t)blk * 256 + d;
    if (tok == 0) { x[oidx] = (bf16_t)1e-5f; return; }
    int bb = b0 + lb; int t = bb >> 8; int s = bb & 255;   // b = t*256+s
    int n = s * 8 + (tok - 1);
    float m0 = mv[((size_t)n * 64 + t) * 2];
    float m1 = mv[((size_t)n * 64 + t) * 2 + 1];
    float v = m0 * w_in[2 * d] + m1 * w_in[2 * d + 1] + b_in[d];
    v = 0.5f * v * (1.0f + erff(v * 0.70710678118654752f));  // exact gelu
    x[oidx] = (bf16_t)v;
}

// ---------------- cls extract: t_x[s*64+t, :] = x[lb, 0, :] (bf16 + fp32) ---------------
__global__ void cls_k(const bf16_t* __restrict__ x, bf16_t* __restrict__ txb,
                      float* __restrict__ txf, int b0) {
    int lb = blockIdx.x; int d = threadIdx.x;
    int bb = b0 + lb; int t = bb >> 8; int s = bb & 255;
    bf16_t v = x[(size_t)lb * 2304 + d];
    size_t di = ((size_t)(s * 64 + t)) * 256 + d;
    txb[di] = v;
    txf[di] = (float)v;
}

// ---------------- plain GEMM: C = A @ W^T + bias (opt relu), bf16 out ------------------
// 1-D grid, XCD-grouped: all NT n-blocks of an m-tile land on the same XCD (g%8 const)
// so the A-tile is fetched into that XCD's L2 once. Swapped MFMA operands: lane holds
// 4 consecutive output cols -> packed dwordx2 stores.
__global__ __launch_bounds__(256) void gemm_bt(const bf16_t* __restrict__ A,
                                               const bf16_t* __restrict__ W,
                                               const float* __restrict__ bias,
                                               bf16_t* __restrict__ C,
                                               int M, int N, int K, int relu) {
    __shared__ __align__(16) bf16_t As[4096];  // [128][32]
    __shared__ __align__(16) bf16_t Ws[4096];  // [128][32]
    int MT = M >> 7, NT = N >> 7;
    int g = blockIdx.x;
    int m_t, n_t;
    if ((MT & 7) == 0) {
        int x = g & 7, q = g >> 3;
        m_t = (q / NT) * 8 + x;
        n_t = q % NT;
    } else {
        m_t = g / NT; n_t = g % NT;
    }
    int tid = threadIdx.x;
    int lane = tid & 63;
    int wave = tid >> 6;
    int m0 = m_t * 128;
    int n0 = n_t * 128;
    int wm = (wave & 1) * 64;
    int wn = (wave >> 1) * 64;
    int arow = tid >> 2;
    int acol = (tid & 3) * 8;
    int fm = lane & 15;
    int fq = lane >> 4;

    floatx4 acc[4][4] = {};

    const bf16_t* Ag = A + (size_t)(m0 + arow) * K + acol;
    const bf16_t* Wg = W + (size_t)(n0 + arow) * K + acol;

    for (int k0 = 0; k0 < K; k0 += 32) {
        __syncthreads();
        ldg_lds16(Ag + k0,                  &As[tid * 8]);
        ldg_lds16(Ag + k0 + (size_t)64 * K, &As[2048 + tid * 8]);
        ldg_lds16(Wg + k0,                  &Ws[tid * 8]);
        ldg_lds16(Wg + k0 + (size_t)64 * K, &Ws[2048 + tid * 8]);
        __syncthreads();

        bf16x8 af[4], wf[4];
#pragma unroll
        for (int mi = 0; mi < 4; mi++)
            af[mi] = *(const bf16x8*)&As[(wm + mi * 16 + fm) * 32 + fq * 8];
#pragma unroll
        for (int ni = 0; ni < 4; ni++)
            wf[ni] = *(const bf16x8*)&Ws[(wn + ni * 16 + fm) * 32 + fq * 8];
#pragma unroll
        for (int mi = 0; mi < 4; mi++)
#pragma unroll
            for (int ni = 0; ni < 4; ni++)
                acc[mi][ni] = __builtin_amdgcn_mfma_f32_16x16x32_bf16(wf[ni], af[mi], acc[mi][ni], 0, 0, 0);
    }

    // swapped layout: lane holds C[row = wm+mi*16+fm][cols = wn+ni*16+fq*4 .. +3]
#pragma unroll
    for (int mi = 0; mi < 4; mi++) {
        int row = m0 + wm + mi * 16 + fm;
#pragma unroll
        for (int ni = 0; ni < 4; ni++) {
            int colb = n0 + wn + ni * 16 + fq * 4;
            float4 b4 = *(const float4*)(bias + colb);
            float v0 = acc[mi][ni][0] + b4.x;
            float v1 = acc[mi][ni][1] + b4.y;
            float v2 = acc[mi][ni][2] + b4.z;
            float v3 = acc[mi][ni][3] + b4.w;
            if (relu) {
                v0 = fmaxf(v0, 0.f); v1 = fmaxf(v1, 0.f);
                v2 = fmaxf(v2, 0.f); v3 = fmaxf(v3, 0.f);
            }
            bf16_t t4[4] = {(bf16_t)v0, (bf16_t)v1, (bf16_t)v2, (bf16_t)v3};
            *(uint2*)(C + (size_t)row * N + colb) = *(uint2*)t4;
        }
    }
}

// ---------------- attention, seqlen 9: 4 seqs / 256-thread block, bf16 LDS -------------
__global__ __launch_bounds__(256) void attn9_k(const bf16_t* __restrict__ qkv,
                                               bf16_t* __restrict__ ao) {
    __shared__ __align__(16) bf16_t sb[27648];  // 4 * 9 * 768
    int b = blockIdx.x; int tid = threadIdx.x;
    const uint4* src = (const uint4*)(qkv + (size_t)b * 27648);
    uint4* dstl = (uint4*)sb;
    for (int c = tid; c < 3456; c += 256) dstl[c] = src[c];
    __syncthreads();
    for (int p = tid; p < 288; p += 256) {
        int s = p / 72; int rem = p - s * 72; int h = rem / 9; int i = rem - h * 9;
        const bf16_t* B = sb + s * 6912;
        const bf16_t* qp = B + i * 768 + h * 32;
        float qf[32];
#pragma unroll
        for (int c = 0; c < 4; c++) {
            bf16x8 t8 = *(const bf16x8*)(qp + c * 8);
#pragma unroll
            for (int e = 0; e < 8; e++) qf[c * 8 + e] = (float)t8[e];
        }
        float sc[9]; float mx = -1e30f;
#pragma unroll
        for (int j = 0; j < 9; j++) {
            const bf16_t* kp = B + j * 768 + 256 + h * 32;
            float d = 0.f;
#pragma unroll
            for (int c = 0; c < 4; c++) {
                bf16x8 t8 = *(const bf16x8*)(kp + c * 8);
#pragma unroll
                for (int e = 0; e < 8; e++) d += qf[c * 8 + e] * (float)t8[e];
            }
            d *= 0.17677669529663687f;
            sc[j] = d; mx = fmaxf(mx, d);
        }
        float den = 0.f;
#pragma unroll
        for (int j = 0; j < 9; j++) { sc[j] = __expf(sc[j] - mx); den += sc[j]; }
        float inv = 1.0f / den;
        float of[32] = {};
#pragma unroll
        for (int j = 0; j < 9; j++) {
            const bf16_t* vp = B + j * 768 + 512 + h * 32;
            float w = sc[j];
#pragma unroll
            for (int c = 0; c < 4; c++) {
                bf16x8 t8 = *(const bf16x8*)(vp + c * 8);
#pragma unroll
                for (int e = 0; e < 8; e++) of[c * 8 + e] += w * (float)t8[e];
            }
        }
        bf16_t* dst = ao + ((size_t)(b * 4 + s) * 9 + i) * 256 + h * 32;
#pragma unroll
        for (int c = 0; c < 4; c++) {
            bf16x8 o8;
#pragma unroll
            for (int e = 0; e < 8; e++) o8[e] = (bf16_t)(of[c * 8 + e] * inv);
            *(bf16x8*)(dst + c * 8) = o8;
        }
    }
}

// ---------------- attention, seqlen 64 (stage C) ---------------------------------------
// Block = 256 threads = 4 waves per (seq, head). Waves split the j (key) dimension for
// scores (16 each), merge softmax stats via LDS, then split the output dim for PV.
__global__ __launch_bounds__(256) void attn64_k(const bf16_t* __restrict__ qkv,
                                                bf16_t* __restrict__ ao) {
    __shared__ __align__(16) float kk[64 * 36];   // padded rows
    __shared__ __align__(16) float vv[64 * 36];
    __shared__ __align__(16) float pp[64 * 64];   // P[j][i]
    __shared__ float mloc[4 * 64];
    __shared__ float sloc[4 * 64];
    int s = blockIdx.x >> 3, h = blockIdx.x & 7;
    int t = threadIdx.x;
    int i = t & 63;          // lane = query row / output row
    int wq = t >> 6;         // wave index = j-quarter (phase 1) / dim-chunk (phase 2)

    {
        int r = t >> 2, c = t & 3;
        const bf16_t* kb = qkv + ((size_t)(s * 64 + r)) * 768 + h * 32 + 256 + c * 8;
        bf16x8 k8 = *(const bf16x8*)kb;
        bf16x8 v8 = *(const bf16x8*)(kb + 256);
        float* kd = &kk[r * 36 + c * 8];
        float* vd = &vv[r * 36 + c * 8];
#pragma unroll
        for (int e = 0; e < 8; e++) { kd[e] = (float)k8[e]; vd[e] = (float)v8[e]; }
    }
    const bf16_t* qb = qkv + ((size_t)(s * 64 + i)) * 768 + h * 32;
    float qf[32];
#pragma unroll
    for (int c = 0; c < 4; c++) {
        bf16x8 t8 = *(const bf16x8*)(qb + c * 8);
#pragma unroll
        for (int e = 0; e < 8; e++) qf[c * 8 + e] = (float)t8[e];
    }
    __syncthreads();

    float sc[16]; float mx = -1e30f;
#pragma unroll
    for (int jj = 0; jj < 16; jj++) {
        int j = wq * 16 + jj;
        const float* kr = &kk[j * 36];
        float d = 0.f;
#pragma unroll
        for (int c = 0; c < 8; c++) {
            float4 k4 = *(const float4*)(kr + c * 4);
            d += qf[c*4+0]*k4.x + qf[c*4+1]*k4.y + qf[c*4+2]*k4.z + qf[c*4+3]*k4.w;
        }
        d *= 0.17677669529663687f;
        sc[jj] = d; mx = fmaxf(mx, d);
    }
    float se = 0.f;
#pragma unroll
    for (int jj = 0; jj < 16; jj++) se += __expf(sc[jj] - mx);
    mloc[wq * 64 + i] = mx;
    sloc[wq * 64 + i] = se;
    __syncthreads();

    float m0 = mloc[i], m1 = mloc[64 + i], m2 = mloc[128 + i], m3 = mloc[192 + i];
    float gm = fmaxf(fmaxf(m0, m1), fmaxf(m2, m3));
    float D = sloc[i] * __expf(m0 - gm) + sloc[64 + i] * __expf(m1 - gm)
            + sloc[128 + i] * __expf(m2 - gm) + sloc[192 + i] * __expf(m3 - gm);

#pragma unroll
    for (int jj = 0; jj < 16; jj++)
        pp[(wq * 16 + jj) * 64 + i] = __expf(sc[jj] - gm);
    __syncthreads();

    float of[8] = {};
    for (int j = 0; j < 64; j++) {
        float w = pp[j * 64 + i];
        const float* vr = &vv[j * 36 + wq * 8];
        float4 va = *(const float4*)vr;
        float4 vb = *(const float4*)(vr + 4);
        of[0] += w * va.x; of[1] += w * va.y; of[2] += w * va.z; of[3] += w * va.w;
        of[4] += w * vb.x; of[5] += w * vb.y; of[6] += w * vb.z; of[7] += w * vb.w;
    }
    float invD = 1.0f / D;
    bf16_t o8[8];
#pragma unroll
    for (int e = 0; e < 8; e++) o8[e] = (bf16_t)(of[e] * invD);
    *(uint4*)(ao + ((size_t)(s * 64 + i)) * 256 + h * 32 + wq * 8) = *(uint4*)o8;
}

// ---------------- residual + LayerNorm: out = LN(xin+add)*w+b; one wave per row --------
__global__ __launch_bounds__(256) void resln_k(const bf16_t* __restrict__ xin_bf,
                                               const float* __restrict__ xin_f,
                                               const bf16_t* __restrict__ add,
                                               const float* __restrict__ w,
                                               const float* __restrict__ b,
                                               bf16_t* __restrict__ out_bf,
                                               float* __restrict__ out_f) {
    int row = blockIdx.x * 4 + (threadIdx.x >> 6);
    int lane = threadIdx.x & 63;
    size_t base = (size_t)row * 256 + lane * 4;
    float xv[4], av[4], v[4];
    if (xin_f) {
        float4 t = *(const float4*)(xin_f + base);
        xv[0] = t.x; xv[1] = t.y; xv[2] = t.z; xv[3] = t.w;
    } else {
        unpack4(*(const uint2*)(xin_bf + base), xv);
    }
    unpack4(*(const uint2*)(add + base), av);
    float s = 0.f, ss = 0.f;
#pragma unroll
    for (int i = 0; i < 4; i++) { v[i] = xv[i] + av[i]; s += v[i]; ss += v[i] * v[i]; }
#pragma unroll
    for (int off = 32; off > 0; off >>= 1) {
        s += __shfl_xor(s, off, 64);
        ss += __shfl_xor(ss, off, 64);
    }
    float mean = s * (1.f / 256.f);
    float var = ss * (1.f / 256.f) - mean * mean;
    float inv = rsqrtf(var + 1e-5f);
    float o[4];
#pragma unroll
    for (int i = 0; i < 4; i++)
        o[i] = (v[i] - mean) * inv * w[lane * 4 + i] + b[lane * 4 + i];
    if (out_bf) {
        bf16_t tmp[4] = {(bf16_t)o[0], (bf16_t)o[1], (bf16_t)o[2], (bf16_t)o[3]};
        *(uint2*)(out_bf + base) = *(uint2*)tmp;
    }
    if (out_f) {
        float4 t; t.x = o[0]; t.y = o[1]; t.z = o[2]; t.w = o[3];
        *(float4*)(out_f + base) = t;
    }
}

// ------------------------------------------------------------------------------------------
extern "C" void kernel_launch(void* const* d_in, const int* in_sizes, int n_in,
                              void* d_out, int out_size, void* d_ws, size_t ws_size,
                              hipStream_t stream) {
    const float* mv   = (const float*)d_in[0];
    const float* w_in = (const float*)d_in[2];
    const float* b_in = (const float*)d_in[3];
    const float* sp[12]; const float* tp[12];
    for (int i = 0; i < 12; i++) { sp[i] = (const float*)d_in[4 + i]; tp[i] = (const float*)d_in[16 + i]; }
    // idx: 0 qkvw, 1 qkvb, 2 ow, 3 ob, 4 l1w, 5 l1b, 6 l2w, 7 l2b, 8 ln1w, 9 ln1b, 10 ln2w, 11 ln2b

    bf16_t* wbf = (bf16_t*)d_ws;              // 1310720 bf16 weights
    bf16_t* txb = wbf + 1310720;              // t_x bf16: 16384*256
    float*  txf = (float*)(txb + 4194304);    // t_x fp32: 16384*256
    bf16_t* pool = (bf16_t*)(txf + 4194304);

    long long headB = 2621440LL + 8388608LL + 16777216LL;  // wbf + txb + txf bytes
    long long cand[5] = {16384, 8192, 4096, 2048, 1024};
    int BC = 1024;
    for (int c = 0; c < 5; c++) {
        long long poolB = cand[c] * 11520LL * 2;            // x(2304)+qkv(6912)+ao(2304) bf16
        if (poolB < 33554432LL) poolB = 33554432LL;         // stage-C floor
        if ((size_t)(headB + poolB) <= ws_size) { BC = (int)cand[c]; break; }
    }

    cvt_weights<<<5120, 256, 0, stream>>>(sp[0], sp[2], sp[4], sp[6], tp[0], tp[2], tp[4], tp[6], wbf);

    const int M = BC * 9;
    const int MTb = M / 128;
    bf16_t* xc    = pool;
    bf16_t* qkvb_ = pool + (long long)BC * 2304;
    bf16_t* aob   = qkvb_ + (long long)BC * 6912;
    bf16_t* pob   = qkvb_;                          // proj out (qkv region free after attn9)
    bf16_t* hb    = qkvb_;                          // ffn hidden (pob dead after resln)
    bf16_t* f2b   = qkvb_ + (long long)M * 128;     // ffn2 out (after hb)

    for (int b0 = 0; b0 < 16384; b0 += BC) {
        embed_k<<<dim3(M), 256, 0, stream>>>(mv, w_in, b_in, xc, b0);
        for (int l = 0; l < 2; l++) {
            const bf16_t* wq = wbf + 0      + l * 196608;
            const bf16_t* wo = wbf + 393216 + l * 65536;
            const bf16_t* w1 = wbf + 524288 + l * 32768;
            const bf16_t* w2 = wbf + 589824 + l * 32768;
            gemm_bt<<<dim3(MTb * 6), 256, 0, stream>>>(xc, wq, sp[1] + l * 768, qkvb_, M, 768, 256, 0);
            attn9_k<<<dim3(BC / 4), 256, 0, stream>>>(qkvb_, aob);
            gemm_bt<<<dim3(MTb * 2), 256, 0, stream>>>(aob, wo, sp[3] + l * 256, pob, M, 256, 256, 0);
            resln_k<<<dim3(M / 4), 256, 0, stream>>>(xc, (const float*)nullptr, pob,
                                                     sp[8] + l * 256, sp[9] + l * 256,
                                                     xc, (float*)nullptr);
            gemm_bt<<<dim3(MTb * 1), 256, 0, stream>>>(xc, w1, sp[5] + l * 128, hb, M, 128, 256, 1);
            gemm_bt<<<dim3(MTb * 2), 256, 0, stream>>>(hb, w2, sp[7] + l * 256, f2b, M, 256, 128, 0);
            resln_k<<<dim3(M / 4), 256, 0, stream>>>(xc, (const float*)nullptr, f2b,
                                                     sp[10] + l * 256, sp[11] + l * 256,
                                                     xc, (float*)nullptr);
        }
        cls_k<<<dim3(BC), 256, 0, stream>>>(xc, txb, txf, b0);
    }

    // ---- stage C: 256 seqs x 64 tokens, fp32 residual sidecar ----
    const int Mt = 16384;
    bf16_t* tqkv = pool;                    // 16384*768
    bf16_t* tao  = pool + 12582912;         // 16384*256
    bf16_t* tpo  = pool;                    // proj out (tqkv region free after attn64)
    bf16_t* tth  = pool + 4194304;          // ffn hidden 16384*128
    bf16_t* tf2  = pool + 4194304 + 2097152;// ffn2 out 16384*256
    for (int l = 0; l < 2; l++) {
        gemm_bt<<<dim3(128 * 6), 256, 0, stream>>>(txb, wbf + 655360 + l * 196608, tp[1] + l * 768,
                                                   tqkv, Mt, 768, 256, 0);
        attn64_k<<<dim3(2048), 256, 0, stream>>>(tqkv, tao);
        gemm_bt<<<dim3(128 * 2), 256, 0, stream>>>(tao, wbf + 1048576 + l * 65536, tp[3] + l * 256,
                                                   tpo, Mt, 256, 256, 0);
        resln_k<<<dim3(4096), 256, 0, stream>>>((const bf16_t*)nullptr, txf, tpo,
                                                tp[8] + l * 256, tp[9] + l * 256,
                                                txb, txf);
        gemm_bt<<<dim3(128 * 1), 256, 0, stream>>>(txb, wbf + 1179648 + l * 32768, tp[5] + l * 128,
                                                   tth, Mt, 128, 256, 1);
        gemm_bt<<<dim3(128 * 2), 256, 0, stream>>>(tth, wbf + 1245184 + l * 32768, tp[7] + l * 256,
                                                   tf2, Mt, 256, 128, 0);
        if (l == 0)
            resln_k<<<dim3(4096), 256, 0, stream>>>((const bf16_t*)nullptr, txf, tf2,
                                                    tp[10] + l * 256, tp[11] + l * 256,
                                                    txb, txf);
        else
            resln_k<<<dim3(4096), 256, 0, stream>>>((const bf16_t*)nullptr, txf, tf2,
                                                    tp[10] + l * 256, tp[11] + l * 256,
                                                    (bf16_t*)nullptr, (float*)d_out);
    }
}

// Round 9
// 1153.535 us; speedup vs baseline: 1.1430x; 1.0521x over previous
//
#include <hip/hip_runtime.h>
#include <hip/hip_bf16.h>
#include <math.h>

typedef __bf16 bf16_t;
typedef float floatx4 __attribute__((ext_vector_type(4)));
typedef bf16_t bf16x8 __attribute__((ext_vector_type(8)));

typedef __attribute__((address_space(1))) void g_void;
typedef __attribute__((address_space(3))) void lds_void;

__device__ __forceinline__ void ldg_lds16(const bf16_t* g, bf16_t* l) {
    __builtin_amdgcn_global_load_lds((g_void*)g, (lds_void*)l, 16, 0, 0);
}

__device__ __forceinline__ void unpack4(uint2 r, float* o) {
    o[0] = __uint_as_float((r.x & 0xffffu) << 16); o[1] = __uint_as_float(r.x & 0xffff0000u);
    o[2] = __uint_as_float((r.y & 0xffffu) << 16); o[3] = __uint_as_float(r.y & 0xffff0000u);
}

// ---------------- weight fp32 -> bf16 conversion --------------------------------------
__global__ void cvt_weights(const float* __restrict__ sqkvw, const float* __restrict__ sow,
                            const float* __restrict__ sl1w,  const float* __restrict__ sl2w,
                            const float* __restrict__ tqkvw, const float* __restrict__ tow,
                            const float* __restrict__ tl1w,  const float* __restrict__ tl2w,
                            bf16_t* __restrict__ dst) {
    int i = blockIdx.x * 256 + threadIdx.x;  // total 1310720
    float v;
    if      (i <  393216) v = sqkvw[i];
    else if (i <  524288) v = sow  [i -  393216];
    else if (i <  589824) v = sl1w [i -  524288];
    else if (i <  655360) v = sl2w [i -  589824];
    else if (i < 1048576) v = tqkvw[i -  655360];
    else if (i < 1179648) v = tow  [i - 1048576];
    else if (i < 1245184) v = tl1w [i - 1179648];
    else                  v = tl2w [i - 1245184];
    dst[i] = (bf16_t)v;
}

// ---------------- embed: gelu(moveinfo @ w_in^T + b_in), cls=1e-5, layout [BC,9,256] ----
__global__ void embed_k(const float* __restrict__ mv, const float* __restrict__ w_in,
                        const float* __restrict__ b_in, bf16_t* __restrict__ x, int b0) {
    int blk = blockIdx.x; int d = threadIdx.x;
    int tok = blk % 9; int lb = blk / 9;
    size_t oidx = (size_t)blk * 256 + d;
    if (tok == 0) { x[oidx] = (bf16_t)1e-5f; return; }
    int bb = b0 + lb; int t = bb >> 8; int s = bb & 255;   // b = t*256+s
    int n = s * 8 + (tok - 1);
    float m0 = mv[((size_t)n * 64 + t) * 2];
    float m1 = mv[((size_t)n * 64 + t) * 2 + 1];
    float v = m0 * w_in[2 * d] + m1 * w_in[2 * d + 1] + b_in[d];
    v = 0.5f * v * (1.0f + erff(v * 0.70710678118654752f));  // exact gelu
    x[oidx] = (bf16_t)v;
}

// ---------------- cls extract: t_x[s*64+t, :] = x[lb, 0, :] (bf16 + fp32) ---------------
__global__ void cls_k(const bf16_t* __restrict__ x, bf16_t* __restrict__ txb,
                      float* __restrict__ txf, int b0) {
    int lb = blockIdx.x; int d = threadIdx.x;
    int bb = b0 + lb; int t = bb >> 8; int s = bb & 255;
    bf16_t v = x[(size_t)lb * 2304 + d];
    size_t di = ((size_t)(s * 64 + t)) * 256 + d;
    txb[di] = v;
    txf[di] = (float)v;
}

// ---------------- plain GEMM: C = A @ W^T + bias (opt relu), bf16 out ------------------
// 1-D grid, XCD-grouped (R8 win: FETCH 113->22MB). Dual K-slab per barrier round (BK=64):
// two independent [128][32] LDS slabs per matrix keep global_load_lds contiguity while
// halving barrier count. Swapped MFMA operands: lane holds 4 consecutive output cols.
__global__ __launch_bounds__(256) void gemm_bt(const bf16_t* __restrict__ A,
                                               const bf16_t* __restrict__ W,
                                               const float* __restrict__ bias,
                                               bf16_t* __restrict__ C,
                                               int M, int N, int K, int relu) {
    __shared__ __align__(16) bf16_t As[8192];  // 2 slabs of [128][32]
    __shared__ __align__(16) bf16_t Ws[8192];
    int MT = M >> 7, NT = N >> 7;
    int g = blockIdx.x;
    int m_t, n_t;
    if ((MT & 7) == 0) {
        int x = g & 7, q = g >> 3;
        m_t = (q / NT) * 8 + x;
        n_t = q % NT;
    } else {
        m_t = g / NT; n_t = g % NT;
    }
    int tid = threadIdx.x;
    int lane = tid & 63;
    int wave = tid >> 6;
    int m0 = m_t * 128;
    int n0 = n_t * 128;
    int wm = (wave & 1) * 64;
    int wn = (wave >> 1) * 64;
    int arow = tid >> 2;
    int acol = (tid & 3) * 8;
    int fm = lane & 15;
    int fq = lane >> 4;

    floatx4 acc[4][4] = {};

    const bf16_t* Ag = A + (size_t)(m0 + arow) * K + acol;
    const bf16_t* Wg = W + (size_t)(n0 + arow) * K + acol;

    for (int k0 = 0; k0 < K; k0 += 64) {
        __syncthreads();
        // slab 0: cols k0..k0+31 ; slab 1: cols k0+32..k0+63
        ldg_lds16(Ag + k0,                       &As[tid * 8]);
        ldg_lds16(Ag + k0 + (size_t)64 * K,      &As[2048 + tid * 8]);
        ldg_lds16(Ag + k0 + 32,                  &As[4096 + tid * 8]);
        ldg_lds16(Ag + k0 + 32 + (size_t)64 * K, &As[6144 + tid * 8]);
        ldg_lds16(Wg + k0,                       &Ws[tid * 8]);
        ldg_lds16(Wg + k0 + (size_t)64 * K,      &Ws[2048 + tid * 8]);
        ldg_lds16(Wg + k0 + 32,                  &Ws[4096 + tid * 8]);
        ldg_lds16(Wg + k0 + 32 + (size_t)64 * K, &Ws[6144 + tid * 8]);
        __syncthreads();

#pragma unroll
        for (int sl = 0; sl < 2; sl++) {
            int base = sl * 4096;
            bf16x8 af[4], wf[4];
#pragma unroll
            for (int mi = 0; mi < 4; mi++)
                af[mi] = *(const bf16x8*)&As[base + (wm + mi * 16 + fm) * 32 + fq * 8];
#pragma unroll
            for (int ni = 0; ni < 4; ni++)
                wf[ni] = *(const bf16x8*)&Ws[base + (wn + ni * 16 + fm) * 32 + fq * 8];
#pragma unroll
            for (int mi = 0; mi < 4; mi++)
#pragma unroll
                for (int ni = 0; ni < 4; ni++)
                    acc[mi][ni] = __builtin_amdgcn_mfma_f32_16x16x32_bf16(wf[ni], af[mi], acc[mi][ni], 0, 0, 0);
        }
    }

    // swapped layout: lane holds C[row = wm+mi*16+fm][cols = wn+ni*16+fq*4 .. +3]
#pragma unroll
    for (int mi = 0; mi < 4; mi++) {
        int row = m0 + wm + mi * 16 + fm;
#pragma unroll
        for (int ni = 0; ni < 4; ni++) {
            int colb = n0 + wn + ni * 16 + fq * 4;
            float4 b4 = *(const float4*)(bias + colb);
            float v0 = acc[mi][ni][0] + b4.x;
            float v1 = acc[mi][ni][1] + b4.y;
            float v2 = acc[mi][ni][2] + b4.z;
            float v3 = acc[mi][ni][3] + b4.w;
            if (relu) {
                v0 = fmaxf(v0, 0.f); v1 = fmaxf(v1, 0.f);
                v2 = fmaxf(v2, 0.f); v3 = fmaxf(v3, 0.f);
            }
            bf16_t t4[4] = {(bf16_t)v0, (bf16_t)v1, (bf16_t)v2, (bf16_t)v3};
            *(uint2*)(C + (size_t)row * N + colb) = *(uint2*)t4;
        }
    }
}

// ---------------- attention, seqlen 9: 4 seqs / 256-thread block, bf16 LDS -------------
__global__ __launch_bounds__(256) void attn9_k(const bf16_t* __restrict__ qkv,
                                               bf16_t* __restrict__ ao) {
    __shared__ __align__(16) bf16_t sb[27648];  // 4 * 9 * 768
    int b = blockIdx.x; int tid = threadIdx.x;
    const uint4* src = (const uint4*)(qkv + (size_t)b * 27648);
    uint4* dstl = (uint4*)sb;
    for (int c = tid; c < 3456; c += 256) dstl[c] = src[c];
    __syncthreads();
    for (int p = tid; p < 288; p += 256) {
        int s = p / 72; int rem = p - s * 72; int h = rem / 9; int i = rem - h * 9;
        const bf16_t* B = sb + s * 6912;
        const bf16_t* qp = B + i * 768 + h * 32;
        float qf[32];
#pragma unroll
        for (int c = 0; c < 4; c++) {
            bf16x8 t8 = *(const bf16x8*)(qp + c * 8);
#pragma unroll
            for (int e = 0; e < 8; e++) qf[c * 8 + e] = (float)t8[e];
        }
        float sc[9]; float mx = -1e30f;
#pragma unroll
        for (int j = 0; j < 9; j++) {
            const bf16_t* kp = B + j * 768 + 256 + h * 32;
            float d = 0.f;
#pragma unroll
            for (int c = 0; c < 4; c++) {
                bf16x8 t8 = *(const bf16x8*)(kp + c * 8);
#pragma unroll
                for (int e = 0; e < 8; e++) d += qf[c * 8 + e] * (float)t8[e];
            }
            d *= 0.17677669529663687f;
            sc[j] = d; mx = fmaxf(mx, d);
        }
        float den = 0.f;
#pragma unroll
        for (int j = 0; j < 9; j++) { sc[j] = __expf(sc[j] - mx); den += sc[j]; }
        float inv = 1.0f / den;
        float of[32] = {};
#pragma unroll
        for (int j = 0; j < 9; j++) {
            const bf16_t* vp = B + j * 768 + 512 + h * 32;
            float w = sc[j];
#pragma unroll
            for (int c = 0; c < 4; c++) {
                bf16x8 t8 = *(const bf16x8*)(vp + c * 8);
#pragma unroll
                for (int e = 0; e < 8; e++) of[c * 8 + e] += w * (float)t8[e];
            }
        }
        bf16_t* dst = ao + ((size_t)(b * 4 + s) * 9 + i) * 256 + h * 32;
#pragma unroll
        for (int c = 0; c < 4; c++) {
            bf16x8 o8;
#pragma unroll
            for (int e = 0; e < 8; e++) o8[e] = (bf16_t)(of[c * 8 + e] * inv);
            *(bf16x8*)(dst + c * 8) = o8;
        }
    }
}

// ---------------- attention, seqlen 64 (stage C) ---------------------------------------
__global__ __launch_bounds__(256) void attn64_k(const bf16_t* __restrict__ qkv,
                                                bf16_t* __restrict__ ao) {
    __shared__ __align__(16) float kk[64 * 36];   // padded rows
    __shared__ __align__(16) float vv[64 * 36];
    __shared__ __align__(16) float pp[64 * 64];   // P[j][i]
    __shared__ float mloc[4 * 64];
    __shared__ float sloc[4 * 64];
    int s = blockIdx.x >> 3, h = blockIdx.x & 7;
    int t = threadIdx.x;
    int i = t & 63;
    int wq = t >> 6;

    {
        int r = t >> 2, c = t & 3;
        const bf16_t* kb = qkv + ((size_t)(s * 64 + r)) * 768 + h * 32 + 256 + c * 8;
        bf16x8 k8 = *(const bf16x8*)kb;
        bf16x8 v8 = *(const bf16x8*)(kb + 256);
        float* kd = &kk[r * 36 + c * 8];
        float* vd = &vv[r * 36 + c * 8];
#pragma unroll
        for (int e = 0; e < 8; e++) { kd[e] = (float)k8[e]; vd[e] = (float)v8[e]; }
    }
    const bf16_t* qb = qkv + ((size_t)(s * 64 + i)) * 768 + h * 32;
    float qf[32];
#pragma unroll
    for (int c = 0; c < 4; c++) {
        bf16x8 t8 = *(const bf16x8*)(qb + c * 8);
#pragma unroll
        for (int e = 0; e < 8; e++) qf[c * 8 + e] = (float)t8[e];
    }
    __syncthreads();

    float sc[16]; float mx = -1e30f;
#pragma unroll
    for (int jj = 0; jj < 16; jj++) {
        int j = wq * 16 + jj;
        const float* kr = &kk[j * 36];
        float d = 0.f;
#pragma unroll
        for (int c = 0; c < 8; c++) {
            float4 k4 = *(const float4*)(kr + c * 4);
            d += qf[c*4+0]*k4.x + qf[c*4+1]*k4.y + qf[c*4+2]*k4.z + qf[c*4+3]*k4.w;
        }
        d *= 0.17677669529663687f;
        sc[jj] = d; mx = fmaxf(mx, d);
    }
    float se = 0.f;
#pragma unroll
    for (int jj = 0; jj < 16; jj++) se += __expf(sc[jj] - mx);
    mloc[wq * 64 + i] = mx;
    sloc[wq * 64 + i] = se;
    __syncthreads();

    float m0 = mloc[i], m1 = mloc[64 + i], m2 = mloc[128 + i], m3 = mloc[192 + i];
    float gm = fmaxf(fmaxf(m0, m1), fmaxf(m2, m3));
    float D = sloc[i] * __expf(m0 - gm) + sloc[64 + i] * __expf(m1 - gm)
            + sloc[128 + i] * __expf(m2 - gm) + sloc[192 + i] * __expf(m3 - gm);

#pragma unroll
    for (int jj = 0; jj < 16; jj++)
        pp[(wq * 16 + jj) * 64 + i] = __expf(sc[jj] - gm);
    __syncthreads();

    float of[8] = {};
    for (int j = 0; j < 64; j++) {
        float w = pp[j * 64 + i];
        const float* vr = &vv[j * 36 + wq * 8];
        float4 va = *(const float4*)vr;
        float4 vb = *(const float4*)(vr + 4);
        of[0] += w * va.x; of[1] += w * va.y; of[2] += w * va.z; of[3] += w * va.w;
        of[4] += w * vb.x; of[5] += w * vb.y; of[6] += w * vb.z; of[7] += w * vb.w;
    }
    float invD = 1.0f / D;
    bf16_t o8[8];
#pragma unroll
    for (int e = 0; e < 8; e++) o8[e] = (bf16_t)(of[e] * invD);
    *(uint4*)(ao + ((size_t)(s * 64 + i)) * 256 + h * 32 + wq * 8) = *(uint4*)o8;
}

// ---------------- residual + LayerNorm: out = LN(xin+add)*w+b; one wave per row --------
__global__ __launch_bounds__(256) void resln_k(const bf16_t* __restrict__ xin_bf,
                                               const float* __restrict__ xin_f,
                                               const bf16_t* __restrict__ add,
                                               const float* __restrict__ w,
                                               const float* __restrict__ b,
                                               bf16_t* __restrict__ out_bf,
                                               float* __restrict__ out_f) {
    int row = blockIdx.x * 4 + (threadIdx.x >> 6);
    int lane = threadIdx.x & 63;
    size_t base = (size_t)row * 256 + lane * 4;
    float xv[4], av[4], v[4];
    if (xin_f) {
        float4 t = *(const float4*)(xin_f + base);
        xv[0] = t.x; xv[1] = t.y; xv[2] = t.z; xv[3] = t.w;
    } else {
        unpack4(*(const uint2*)(xin_bf + base), xv);
    }
    unpack4(*(const uint2*)(add + base), av);
    float s = 0.f, ss = 0.f;
#pragma unroll
    for (int i = 0; i < 4; i++) { v[i] = xv[i] + av[i]; s += v[i]; ss += v[i] * v[i]; }
#pragma unroll
    for (int off = 32; off > 0; off >>= 1) {
        s += __shfl_xor(s, off, 64);
        ss += __shfl_xor(ss, off, 64);
    }
    float mean = s * (1.f / 256.f);
    float var = ss * (1.f / 256.f) - mean * mean;
    float inv = rsqrtf(var + 1e-5f);
    float o[4];
#pragma unroll
    for (int i = 0; i < 4; i++)
        o[i] = (v[i] - mean) * inv * w[lane * 4 + i] + b[lane * 4 + i];
    if (out_bf) {
        bf16_t tmp[4] = {(bf16_t)o[0], (bf16_t)o[1], (bf16_t)o[2], (bf16_t)o[3]};
        *(uint2*)(out_bf + base) = *(uint2*)tmp;
    }
    if (out_f) {
        float4 t; t.x = o[0]; t.y = o[1]; t.z = o[2]; t.w = o[3];
        *(float4*)(out_f + base) = t;
    }
}

// ------------------------------------------------------------------------------------------
extern "C" void kernel_launch(void* const* d_in, const int* in_sizes, int n_in,
                              void* d_out, int out_size, void* d_ws, size_t ws_size,
                              hipStream_t stream) {
    const float* mv   = (const float*)d_in[0];
    const float* w_in = (const float*)d_in[2];
    const float* b_in = (const float*)d_in[3];
    const float* sp[12]; const float* tp[12];
    for (int i = 0; i < 12; i++) { sp[i] = (const float*)d_in[4 + i]; tp[i] = (const float*)d_in[16 + i]; }
    // idx: 0 qkvw, 1 qkvb, 2 ow, 3 ob, 4 l1w, 5 l1b, 6 l2w, 7 l2b, 8 ln1w, 9 ln1b, 10 ln2w, 11 ln2b

    bf16_t* wbf = (bf16_t*)d_ws;              // 1310720 bf16 weights
    bf16_t* txb = wbf + 1310720;              // t_x bf16: 16384*256
    float*  txf = (float*)(txb + 4194304);    // t_x fp32: 16384*256
    bf16_t* pool = (bf16_t*)(txf + 4194304);

    long long headB = 2621440LL + 8388608LL + 16777216LL;  // wbf + txb + txf bytes
    long long cand[5] = {16384, 8192, 4096, 2048, 1024};
    int BC = 1024;
    for (int c = 0; c < 5; c++) {
        long long poolB = cand[c] * 11520LL * 2;            // x(2304)+qkv(6912)+ao(2304) bf16
        if (poolB < 33554432LL) poolB = 33554432LL;         // stage-C floor
        if ((size_t)(headB + poolB) <= ws_size) { BC = (int)cand[c]; break; }
    }

    cvt_weights<<<5120, 256, 0, stream>>>(sp[0], sp[2], sp[4], sp[6], tp[0], tp[2], tp[4], tp[6], wbf);

    const int M = BC * 9;
    const int MTb = M / 128;
    bf16_t* xc    = pool;
    bf16_t* qkvb_ = pool + (long long)BC * 2304;
    bf16_t* aob   = qkvb_ + (long long)BC * 6912;
    bf16_t* pob   = qkvb_;                          // proj out (qkv region free after attn9)
    bf16_t* hb    = qkvb_;                          // ffn hidden (pob dead after resln)
    bf16_t* f2b   = qkvb_ + (long long)M * 128;     // ffn2 out (after hb)

    for (int b0 = 0; b0 < 16384; b0 += BC) {
        embed_k<<<dim3(M), 256, 0, stream>>>(mv, w_in, b_in, xc, b0);
        for (int l = 0; l < 2; l++) {
            const bf16_t* wq = wbf + 0      + l * 196608;
            const bf16_t* wo = wbf + 393216 + l * 65536;
            const bf16_t* w1 = wbf + 524288 + l * 32768;
            const bf16_t* w2 = wbf + 589824 + l * 32768;
            gemm_bt<<<dim3(MTb * 6), 256, 0, stream>>>(xc, wq, sp[1] + l * 768, qkvb_, M, 768, 256, 0);
            attn9_k<<<dim3(BC / 4), 256, 0, stream>>>(qkvb_, aob);
            gemm_bt<<<dim3(MTb * 2), 256, 0, stream>>>(aob, wo, sp[3] + l * 256, pob, M, 256, 256, 0);
            resln_k<<<dim3(M / 4), 256, 0, stream>>>(xc, (const float*)nullptr, pob,
                                                     sp[8] + l * 256, sp[9] + l * 256,
                                                     xc, (float*)nullptr);
            gemm_bt<<<dim3(MTb * 1), 256, 0, stream>>>(xc, w1, sp[5] + l * 128, hb, M, 128, 256, 1);
            gemm_bt<<<dim3(MTb * 2), 256, 0, stream>>>(hb, w2, sp[7] + l * 256, f2b, M, 256, 128, 0);
            resln_k<<<dim3(M / 4), 256, 0, stream>>>(xc, (const float*)nullptr, f2b,
                                                     sp[10] + l * 256, sp[11] + l * 256,
                                                     xc, (float*)nullptr);
        }
        cls_k<<<dim3(BC), 256, 0, stream>>>(xc, txb, txf, b0);
    }

    // ---- stage C: 256 seqs x 64 tokens, fp32 residual sidecar ----
    const int Mt = 16384;
    bf16_t* tqkv = pool;                    // 16384*768
    bf16_t* tao  = pool + 12582912;         // 16384*256
    bf16_t* tpo  = pool;                    // proj out (tqkv region free after attn64)
    bf16_t* tth  = pool + 4194304;          // ffn hidden 16384*128
    bf16_t* tf2  = pool + 4194304 + 2097152;// ffn2 out 16384*256
    for (int l = 0; l < 2; l++) {
        gemm_bt<<<dim3(128 * 6), 256, 0, stream>>>(txb, wbf + 655360 + l * 196608, tp[1] + l * 768,
                                                   tqkv, Mt, 768, 256, 0);
        attn64_k<<<dim3(2048), 256, 0, stream>>>(tqkv, tao);
        gemm_bt<<<dim3(128 * 2), 256, 0, stream>>>(tao, wbf + 1048576 + l * 65536, tp[3] + l * 256,
                                                   tpo, Mt, 256, 256, 0);
        resln_k<<<dim3(4096), 256, 0, stream>>>((const bf16_t*)nullptr, txf, tpo,
                                                tp[8] + l * 256, tp[9] + l * 256,
                                                txb, txf);
        gemm_bt<<<dim3(128 * 1), 256, 0, stream>>>(txb, wbf + 1179648 + l * 32768, tp[5] + l * 128,
                                                   tth, Mt, 128, 256, 1);
        gemm_bt<<<dim3(128 * 2), 256, 0, stream>>>(tth, wbf + 1245184 + l * 32768, tp[7] + l * 256,
                                                   tf2, Mt, 256, 128, 0);
        if (l == 0)
            resln_k<<<dim3(4096), 256, 0, stream>>>((const bf16_t*)nullptr, txf, tf2,
                                                    tp[10] + l * 256, tp[11] + l * 256,
                                                    txb, txf);
        else
            resln_k<<<dim3(4096), 256, 0, stream>>>((const bf16_t*)nullptr, txf, tf2,
                                                    tp[10] + l * 256, tp[11] + l * 256,
                                                    (bf16_t*)nullptr, (float*)d_out);
    }
}